// Round 4
// baseline (461.887 us; speedup 1.0000x reference)
//
#include <hip/hip_runtime.h>
#include <hip/hip_bf16.h>
#include <stdint.h>

#define NN     30000
#define MPAD   30080          // 470 * 64
#define RR     8
#define NBASES 30
#define KD     256
#define EE     480000
#define NSEG   (NN * RR)
#define K1     2048           // rel-chunk span of K (8 rels x 256)
#define KTOT   2304           // K1 + 256 root (both layers); 36 x 64
#define BK     64             // K-step; 8 chunks of 8 bf16 per row
#define CAP    32             // fixed segment capacity (Poisson(2): P(>32)~1e-20)

typedef unsigned short u16;
typedef __attribute__((ext_vector_type(8))) short bf16x8;   // 8 bf16 = 4 VGPRs
typedef __attribute__((ext_vector_type(4))) float f32x4;

__device__ __forceinline__ u16 f2b(float f) {
  union { float f; uint32_t u; } v; v.f = f;
  return (u16)((v.u + 0x7fffu + ((v.u >> 16) & 1u)) >> 16);   // RNE
}
__device__ __forceinline__ float b2f(u16 h) {
  union { uint32_t u; float f; } v; v.u = ((uint32_t)h) << 16;
  return v.f;
}

__device__ __forceinline__ void gl_lds16(const void* g, void* l) {
  __builtin_amdgcn_global_load_lds((__attribute__((address_space(1))) void*)g,
                                   (__attribute__((address_space(3))) void*)l,
                                   16, 0, 0);
}

// ------- FUSED mean+GEMM: C[64 x NT] = [meanH | X] @ BT^T ------------------
// r4: delete the H intermediate entirely (r1-r3 proved the GEMM is pinned at
// ~2 TB/s by 128B-granule DRAM-row thrash on the 138MB H stream, and k_mean
// (~85us each, inferred) pays another 368MB to build it).
//   - A-tile for k0 < K1 (rel r = k0>>8) is built IN-KERNEL: thread (row,oc)
//     gathers cnt[d,r] source rows of X (L3-resident, 15MB) and sums f32 in
//     BITWISE-IDENTICAL order/rounding to the old k_mean, then ds_writes the
//     bf16 chunk with the same XOR-8 swizzle the compute phase reads.
//   - A-tile for k0 >= K1 (root/self part) keeps global_load_lds staging.
//   - B staged via global_load_lds (BT tiny, L2-hot). 2-phase dbuf +
//     __syncthreads (drain waits now hit L2/L3 latency, not contended HBM).
// X: [MPAD x 256] bf16 (xb or z1b), BT: [N x KTOT] bf16 (K-major).
// LAST=false: +bias, leaky, bf16 -> ob [MPAD x 256]
// LAST=true : +bias -> of [NN x 128] f32
template<int NT, bool LAST>
__global__ __launch_bounds__(512, 4)
void k_fused(const u16* __restrict__ X, const int* __restrict__ cnt,
             const int* __restrict__ esrc, const u16* __restrict__ BT,
             const float* __restrict__ bias, u16* __restrict__ ob,
             float* __restrict__ of) {
  constexpr int NI = NT / 32;           // n-frags per wave (wave n-span NT/2)
  constexpr int NKI = KTOT / BK;        // 36
  __shared__ u16 Alds[2][64 * BK];
  __shared__ u16 Blds[2][NT * BK];
  __shared__ int   cntL[512];           // per (row 0..63, rel 0..7)
  __shared__ float invL[512];
  const int tid = threadIdx.x;          // 512 threads = 8 waves
  const int w = tid >> 6, lane = tid & 63;
  const int bn = blockIdx.x * NT, bm = blockIdx.y * 64;
  const int wm = (w >> 1) * 16;         // 4 m-waves x 16 rows
  const int wn = (w & 1) * (NT / 2);    // 2 n-waves
  const int l15 = lane & 15, l4 = lane >> 4;
  const int grow = tid >> 3, goc = tid & 7;   // gather: row 0..63, col-octet 0..7

  f32x4 acc[NI];
  #pragma unroll
  for (int ni = 0; ni < NI; ++ni) acc[ni] = (f32x4){0.f, 0.f, 0.f, 0.f};

  // ---- per-block (dst,rel) tables: n and 1/n ----
  {
    int gd = bm + grow;
    int n = 0;
    if (gd < NN) n = cnt[(gd << 3) + (tid & 7)];
    n = n < CAP ? n : CAP;
    cntL[tid] = n;
    invL[tid] = (n > 0) ? 1.f / (float)n : 0.f;
  }

  // ---- B tile stage: NT*8 chunks of 16B via global_load_lds ----
  auto stage_B = [&](int buf, int k0) {
    #pragma unroll
    for (int it = 0; it < NT / 64; ++it) {
      int chb = it * 512 + w * 64;       // wave-uniform dest base
      int ch = chb + lane;
      int row = ch >> 3, pc = ch & 7;
      int lc = pc ^ (row & 7);
      gl_lds16(&BT[(size_t)(bn + row) * KTOT + k0 + lc * 8], &Blds[buf][chb * 8]);
    }
  };

  // ---- A root-part stage (k0 >= K1): 512 chunks, 1 per thread ----
  auto stage_Aroot = [&](int buf, int k0) {
    int chb = w * 64;
    int ch = chb + lane;
    int row = ch >> 3, pc = ch & 7;
    int lc = pc ^ (row & 7);
    gl_lds16(&X[(size_t)(bm + row) * KD + (k0 - K1) + lc * 8], &Alds[buf][chb * 8]);
  };

  // ---- A gather-mean build (k0 < K1): 8 cols/thread, bitwise == k_mean ----
  auto abuild = [&](int k0, uint4& o) {
    int r = k0 >> 8;
    int c0 = (k0 & 255) + goc * 8;       // col within X row (elements)
    int sL = (grow << 3) + r;
    int n = cntL[sL];
    float inv = invL[sL];
    int base = (((bm + grow) << 3) + r) * CAP;
    float a0 = 0.f, a1 = 0.f, a2 = 0.f, a3 = 0.f;
    float a4 = 0.f, a5 = 0.f, a6 = 0.f, a7 = 0.f;
    #pragma unroll 1
    for (int e = 0; e < n; e += 2) {
      int s0 = esrc[base + e];
      bool has1 = (e + 1 < n);
      int s1 = has1 ? esrc[base + e + 1] : s0;
      uint4 v0 = *(const uint4*)&X[(size_t)s0 * KD + c0];
      uint4 v1 = *(const uint4*)&X[(size_t)s1 * KD + c0];
      a0 += b2f((u16)v0.x); a1 += b2f((u16)(v0.x >> 16));
      a2 += b2f((u16)v0.y); a3 += b2f((u16)(v0.y >> 16));
      a4 += b2f((u16)v0.z); a5 += b2f((u16)(v0.z >> 16));
      a6 += b2f((u16)v0.w); a7 += b2f((u16)(v0.w >> 16));
      float m = has1 ? 1.f : 0.f;
      a0 = fmaf(m, b2f((u16)v1.x), a0); a1 = fmaf(m, b2f((u16)(v1.x >> 16)), a1);
      a2 = fmaf(m, b2f((u16)v1.y), a2); a3 = fmaf(m, b2f((u16)(v1.y >> 16)), a3);
      a4 = fmaf(m, b2f((u16)v1.z), a4); a5 = fmaf(m, b2f((u16)(v1.z >> 16)), a5);
      a6 = fmaf(m, b2f((u16)v1.w), a6); a7 = fmaf(m, b2f((u16)(v1.w >> 16)), a7);
    }
    o.x = ((uint32_t)f2b(a1 * inv) << 16) | (uint32_t)f2b(a0 * inv);
    o.y = ((uint32_t)f2b(a3 * inv) << 16) | (uint32_t)f2b(a2 * inv);
    o.z = ((uint32_t)f2b(a5 * inv) << 16) | (uint32_t)f2b(a4 * inv);
    o.w = ((uint32_t)f2b(a7 * inv) << 16) | (uint32_t)f2b(a6 * inv);
  };
  auto awrite = [&](int buf, uint4 o) {
    *(uint4*)&Alds[buf][grow * BK + (goc ^ (grow & 7)) * 8] = o;
  };

  // ---- prologue: tables + B0, then A0 ----
  stage_B(0, 0);
  __syncthreads();                      // tables visible; B0 drained
  {
    uint4 o0; abuild(0, o0); awrite(0, o0);
  }
  __syncthreads();                      // A0 visible

  int buf = 0;
  for (int t = 0; t < NKI; ++t) {
    const bool pf = (t + 1 < NKI);
    const int kn = (t + 1) * BK;
    uint4 o; bool og = false;
    if (pf) {
      stage_B(buf ^ 1, kn);              // L2-hot, lands under compute
      if (kn < K1) { abuild(kn, o); og = true; }   // gather-sum into regs
      else stage_Aroot(buf ^ 1, kn);
    }
    // compute tile t from buf
    #pragma unroll
    for (int s = 0; s < 2; ++s) {
      bf16x8 av, bv[NI];
      {
        int row = wm + l15;
        int pc = (4 * s + l4) ^ (row & 7);
        av = *(const bf16x8*)&Alds[buf][row * BK + pc * 8];
      }
      #pragma unroll
      for (int ni = 0; ni < NI; ++ni) {
        int row = wn + ni * 16 + l15;
        int pc = (4 * s + l4) ^ (row & 7);
        bv[ni] = *(const bf16x8*)&Blds[buf][row * BK + pc * 8];
      }
      #pragma unroll
      for (int ni = 0; ni < NI; ++ni)
        acc[ni] = __builtin_amdgcn_mfma_f32_16x16x32_bf16(av, bv[ni], acc[ni], 0, 0, 0);
    }
    if (og) awrite(buf ^ 1, o);          // write-late (T14)
    __syncthreads();
    buf ^= 1;
  }

  // epilogue: C/D layout col=lane&15, row=(lane>>4)*4+reg
  #pragma unroll
  for (int ni = 0; ni < NI; ++ni) {
    int col = bn + wn + ni * 16 + l15;
    float bb = bias[col];
    #pragma unroll
    for (int v = 0; v < 4; ++v) {
      int row = bm + wm + l4 * 4 + v;
      float val = acc[ni][v] + bb;
      if (!LAST) {
        val = val > 0.f ? val : 0.01f * val;
        ob[(size_t)row * KD + col] = f2b(val);   // rows >= NN: finite garbage, ok
      } else if (row < NN) {
        of[(size_t)row * 128 + col] = val;
      }
    }
  }
}

// ------- small kernels ------------------------------------------------------
__global__ void k_cast_x(const float* __restrict__ x, u16* __restrict__ xb) {
  int t = blockIdx.x * 256 + threadIdx.x;
  if (t < NN * KD / 4) {
    float4 v = ((const float4*)x)[t];
    union { u16 h[4]; uint2 u; } p;
    p.h[0] = f2b(v.x); p.h[1] = f2b(v.y); p.h[2] = f2b(v.z); p.h[3] = f2b(v.w);
    ((uint2*)xb)[t] = p.u;
  }
}

// BT1[o, k] k<2048: sum_b comp1[r,b]*bases1[b,i,o]; k in [2048,2304): root1[i,o]
__global__ void k_combine1(const float* __restrict__ bases, const float* __restrict__ comp,
                           const float* __restrict__ root, u16* __restrict__ BT) {
  int k = blockIdx.x, o = threadIdx.x;   // 2304 blocks x 256 threads
  float v;
  if (k < K1) {
    int r = k >> 8, i = k & 255;
    float acc = 0.f;
    #pragma unroll
    for (int b = 0; b < NBASES; ++b)
      acc += comp[r * NBASES + b] * bases[(size_t)b * 65536 + i * 256 + o];
    v = acc;
  } else {
    v = root[(k - K1) * 256 + o];
  }
  BT[(size_t)o * KTOT + k] = f2b(v);
}

__global__ void k_combine2(const float* __restrict__ bases, const float* __restrict__ comp,
                           const float* __restrict__ root, u16* __restrict__ BT) {
  int k = blockIdx.x, o = threadIdx.x;   // 2304 blocks x 128 threads
  float v;
  if (k < K1) {
    int r = k >> 8, i = k & 255;
    float acc = 0.f;
    #pragma unroll
    for (int b = 0; b < NBASES; ++b)
      acc += comp[r * NBASES + b] * bases[(size_t)b * 32768 + i * 128 + o];
    v = acc;
  } else {
    v = root[(k - K1) * 128 + o];
  }
  BT[(size_t)o * KTOT + k] = f2b(v);
}

// fixed-stride bucket: cnt doubles as cursor (replaces hist+scan1/2/3+bucket)
__global__ void k_bucket_fs(const int* __restrict__ ei, const int* __restrict__ ety,
                            int* __restrict__ cnt, int* __restrict__ esrc) {
  int e = blockIdx.x * 256 + threadIdx.x;
  if (e < EE) {
    int seg = ei[EE + e] * RR + ety[e];
    int pos = atomicAdd(&cnt[seg], 1);
    if (pos < CAP) esrc[seg * CAP + pos] = ei[e];
  }
}

// ------- launch -------------------------------------------------------------
extern "C" void kernel_launch(void* const* d_in, const int* in_sizes, int n_in,
                              void* d_out, int out_size, void* d_ws, size_t ws_size,
                              hipStream_t stream) {
  const float* x      = (const float*)d_in[0];
  const int*   ei     = (const int*)d_in[1];
  const int*   ety    = (const int*)d_in[2];
  const float* bases1 = (const float*)d_in[3];
  const float* comp1  = (const float*)d_in[4];
  const float* root1  = (const float*)d_in[5];
  const float* bias1  = (const float*)d_in[6];
  const float* bases2 = (const float*)d_in[7];
  const float* comp2  = (const float*)d_in[8];
  const float* root2  = (const float*)d_in[9];
  const float* bias2  = (const float*)d_in[10];
  float* out = (float*)d_out;

  char* p = (char*)d_ws;
  auto alloc = [&](size_t bytes) {
    char* q = p; p += (bytes + 255) & ~(size_t)255; return q;
  };
  u16* xb   = (u16*)alloc((size_t)MPAD * KD * 2);
  u16* z1b  = (u16*)alloc((size_t)MPAD * KD * 2);
  u16* BT1  = (u16*)alloc((size_t)256 * KTOT * 2);
  u16* BT2  = (u16*)alloc((size_t)128 * KTOT * 2);
  int* cnt  = (int*)alloc((size_t)NSEG * 4);
  int* esrc = (int*)alloc((size_t)NSEG * CAP * 4);     // 30.7 MB fixed-stride

  // fixed-stride CSR (no scans)
  hipMemsetAsync(cnt, 0, (size_t)NSEG * 4, stream);
  k_bucket_fs<<<(EE + 255) / 256, 256, 0, stream>>>(ei, ety, cnt, esrc);

  // weights + input cast
  k_cast_x<<<NN * KD / 4 / 256, 256, 0, stream>>>(x, xb);
  k_combine1<<<KTOT, 256, 0, stream>>>(bases1, comp1, root1, BT1);
  k_combine2<<<KTOT, 128, 0, stream>>>(bases2, comp2, root2, BT2);

  // layer 1: z1b = leaky([mean(xb) | xb] @ BT1^T + bias1)   (mean fused)
  k_fused<128, false><<<dim3(2, 470), 512, 0, stream>>>(xb, cnt, esrc, BT1, bias1, z1b, nullptr);

  // layer 2: out = [mean(z1b) | z1b] @ BT2^T + bias2        (mean fused)
  k_fused<128, true><<<dim3(1, 470), 512, 0, stream>>>(z1b, cnt, esrc, BT2, bias2, nullptr, out);
}

// Round 5
// 374.412 us; speedup vs baseline: 1.2336x; 1.2336x over previous
//
#include <hip/hip_runtime.h>
#include <hip/hip_bf16.h>
#include <stdint.h>

#define NN     30000
#define MPAD   30080          // 470 * 64
#define RR     8
#define NBASES 30
#define KD     256            // K of both GEMMs (in-dim of each layer)
#define EE     480000
#define NSEG   (NN * RR)
#define BK     64             // K-step; 8 chunks of 8 bf16 per row
#define CAP    32             // fixed segment capacity (Poisson(2): P(>32)~1e-20)
#define NC1    2304           // Y1 cols: 8*256 rel + 256 self
#define NC2    1152           // Y2 cols: 8*128 rel + 128 self

typedef unsigned short u16;
typedef __attribute__((ext_vector_type(8))) short bf16x8;   // 8 bf16 = 4 VGPRs
typedef __attribute__((ext_vector_type(4))) float f32x4;

__device__ __forceinline__ u16 f2b(float f) {
  union { float f; uint32_t u; } v; v.f = f;
  return (u16)((v.u + 0x7fffu + ((v.u >> 16) & 1u)) >> 16);   // RNE
}
__device__ __forceinline__ float b2f(u16 h) {
  union { uint32_t u; float f; } v; v.u = ((uint32_t)h) << 16;
  return v.f;
}

__device__ __forceinline__ void gl_lds16(const void* g, void* l) {
  __builtin_amdgcn_global_load_lds((__attribute__((address_space(1))) void*)g,
                                   (__attribute__((address_space(3))) void*)l,
                                   16, 0, 0);
}

// ------- dense transform GEMM: Y[M x NCOLS] = A[M x 256] @ Bn^T ------------
// r5 transform-first: Y[n, j] = sum_k A[n,k] * Bn[j,k].  Perfectly regular
// streaming GEMM (K=256, 4 K-tiles), verified XOR-8 swizzle staging, 2-phase
// dbuf, 8 waves.  Epilogue routes acc through LDS so Y is written in 256B
// contiguous row chunks (raw C/D-layout stores are 2B scattered).
// No bias / activation here — they move to k_agg.
template<int NCOLS>
__global__ __launch_bounds__(512, 6)
void k_gemm_y(const u16* __restrict__ A, const u16* __restrict__ Bn,
              u16* __restrict__ Y) {
  constexpr int NT = 128;               // n-tile
  constexpr int NI = 4;                 // n-frags per wave (wave n-span 64)
  constexpr int NKI = KD / BK;          // 4
  __shared__ __align__(16) char smem[49152];
  u16 (*Alds)[64 * BK] = (u16(*)[64 * BK])smem;                  // 2 x 8KB
  u16 (*Blds)[NT * BK] = (u16(*)[NT * BK])(smem + 2 * 64 * BK * 2); // 2 x 16KB
  float* eps = (float*)smem;            // epilogue f32 tile [64][132]
  const int tid = threadIdx.x;          // 512 threads = 8 waves
  const int w = tid >> 6, lane = tid & 63;
  const int bn = blockIdx.x * NT, bm = blockIdx.y * 64;
  const int wm = (w >> 1) * 16;         // 4 m-waves x 16 rows
  const int wn = (w & 1) * 64;          // 2 n-waves
  const int l15 = lane & 15, l4 = lane >> 4;

  f32x4 acc[NI];
  #pragma unroll
  for (int ni = 0; ni < NI; ++ni) acc[ni] = (f32x4){0.f, 0.f, 0.f, 0.f};

  auto stage = [&](int buf, int k0) {
    // A tile: 64 rows x 8 chunks = 512 chunks of 16B, 1 per thread
    {
      int chb = w * 64;                  // wave-uniform dest base
      int ch = chb + lane;
      int row = ch >> 3, pc = ch & 7;
      int lc = pc ^ (row & 7);
      gl_lds16(&A[(size_t)(bm + row) * KD + k0 + lc * 8], &Alds[buf][chb * 8]);
    }
    // B tile: 128 rows x 8 chunks = 1024 chunks, 2 per thread
    #pragma unroll
    for (int it = 0; it < 2; ++it) {
      int chb = it * 512 + w * 64;
      int ch = chb + lane;
      int row = ch >> 3, pc = ch & 7;
      int lc = pc ^ (row & 7);
      gl_lds16(&Bn[(size_t)(bn + row) * KD + k0 + lc * 8], &Blds[buf][chb * 8]);
    }
  };

  stage(0, 0);
  __syncthreads();
  int buf = 0;
  for (int t = 0; t < NKI; ++t) {
    if (t + 1 < NKI) stage(buf ^ 1, (t + 1) * BK);
    #pragma unroll
    for (int s = 0; s < 2; ++s) {        // two 32-K steps
      bf16x8 av, bv[NI];
      {
        int row = wm + l15;
        int pc = (4 * s + l4) ^ (row & 7);
        av = *(const bf16x8*)&Alds[buf][row * BK + pc * 8];
      }
      #pragma unroll
      for (int ni = 0; ni < NI; ++ni) {
        int row = wn + ni * 16 + l15;
        int pc = (4 * s + l4) ^ (row & 7);
        bv[ni] = *(const bf16x8*)&Blds[buf][row * BK + pc * 8];
      }
      #pragma unroll
      for (int ni = 0; ni < NI; ++ni)
        acc[ni] = __builtin_amdgcn_mfma_f32_16x16x32_bf16(av, bv[ni], acc[ni], 0, 0, 0);
    }
    __syncthreads();
    buf ^= 1;
  }

  // epilogue via LDS: acc (C/D layout col=lane&15, row=(lane>>4)*4+reg) ->
  // f32 tile [64][132] -> bf16 256B-contiguous row-chunk stores.
  #pragma unroll
  for (int ni = 0; ni < NI; ++ni) {
    int col = wn + ni * 16 + l15;
    #pragma unroll
    for (int v = 0; v < 4; ++v) {
      int row = wm + l4 * 4 + v;
      eps[row * 132 + col] = acc[ni][v];
    }
  }
  __syncthreads();
  {
    int row = tid >> 3, oc = tid & 7;    // 64 rows x 8 col-octets
    const float* src = &eps[row * 132 + oc * 16];
    uint4 o[2];
    #pragma unroll
    for (int h = 0; h < 2; ++h) {
      float f0 = src[h*8+0], f1 = src[h*8+1], f2 = src[h*8+2], f3 = src[h*8+3];
      float f4 = src[h*8+4], f5 = src[h*8+5], f6 = src[h*8+6], f7 = src[h*8+7];
      o[h].x = ((uint32_t)f2b(f1) << 16) | (uint32_t)f2b(f0);
      o[h].y = ((uint32_t)f2b(f3) << 16) | (uint32_t)f2b(f2);
      o[h].z = ((uint32_t)f2b(f5) << 16) | (uint32_t)f2b(f4);
      o[h].w = ((uint32_t)f2b(f7) << 16) | (uint32_t)f2b(f6);
    }
    u16* dst = &Y[(size_t)(bm + row) * NCOLS + bn + oc * 16];
    *(uint4*)dst = o[0];
    *(uint4*)(dst + 8) = o[1];
  }
}

// ------- aggregate: out[d] = sum_r mean_e Y[src_e, r-blk] + Yself + bias ---
// block = dst d, 256 threads = 8 halfwaves (one per rel).  Halfwave r sums
// its segment's Y rows (f32 accum of bf16, 512B/edge for D=256), scales by
// 1/n, LDS-reduces across rels, adds self column block + bias, activation.
// Means stay f32 end-to-end (no bf16 intermediate like the old H path).
template<int D, bool LAST>
__global__ __launch_bounds__(256)
void k_agg(const u16* __restrict__ Y, const int* __restrict__ cnt,
           const int* __restrict__ esrc, const float* __restrict__ bias,
           u16* __restrict__ ob, float* __restrict__ of) {
  constexpr int YW = 9 * D;             // Y row width
  constexpr int CW = D / 32;            // cols per lane (8 or 4)
  __shared__ float part[8 * D];
  const int d = blockIdx.x, tid = threadIdx.x;
  const int r = tid >> 5, ln = tid & 31;
  const int s = (d << 3) + r;
  int n = cnt[s]; n = n < CAP ? n : CAP;
  const int base = s * CAP;

  float a[CW];
  #pragma unroll
  for (int j = 0; j < CW; ++j) a[j] = 0.f;
  #pragma unroll 1
  for (int e = 0; e < n; ++e) {
    int sr = esrc[base + e];
    const u16* row = &Y[(size_t)sr * YW + r * D + ln * CW];
    if constexpr (CW == 8) {
      uint4 v = *(const uint4*)row;
      a[0] += b2f((u16)v.x); a[1] += b2f((u16)(v.x >> 16));
      a[2] += b2f((u16)v.y); a[3] += b2f((u16)(v.y >> 16));
      a[4] += b2f((u16)v.z); a[5] += b2f((u16)(v.z >> 16));
      a[6] += b2f((u16)v.w); a[7] += b2f((u16)(v.w >> 16));
    } else {
      uint2 v = *(const uint2*)row;
      a[0] += b2f((u16)v.x); a[1] += b2f((u16)(v.x >> 16));
      a[2] += b2f((u16)v.y); a[3] += b2f((u16)(v.y >> 16));
    }
  }
  float inv = (n > 0) ? 1.f / (float)n : 0.f;
  #pragma unroll
  for (int j = 0; j < CW; ++j) part[r * D + ln * CW + j] = a[j] * inv;
  __syncthreads();
  if (tid < D) {
    float v = 0.f;
    #pragma unroll
    for (int rr = 0; rr < 8; ++rr) v += part[rr * D + tid];
    v += b2f(Y[(size_t)d * YW + 8 * D + tid]);   // self term
    v += bias[tid];
    if (!LAST) {
      v = v > 0.f ? v : 0.01f * v;
      ob[(size_t)d * KD + tid] = f2b(v);
    } else {
      of[(size_t)d * D + tid] = v;
    }
  }
}

// ------- small kernels ------------------------------------------------------
__global__ void k_cast_x(const float* __restrict__ x, u16* __restrict__ xb) {
  int t = blockIdx.x * 256 + threadIdx.x;
  if (t < NN * KD / 4) {
    float4 v = ((const float4*)x)[t];
    union { u16 h[4]; uint2 u; } p;
    p.h[0] = f2b(v.x); p.h[1] = f2b(v.y); p.h[2] = f2b(v.z); p.h[3] = f2b(v.w);
    ((uint2*)xb)[t] = p.u;
  }
}

// Bn1[j*256 + k]: j=r*256+o -> sum_b comp1[r,b]*bases1[b,k,o]; j=2048+o -> root1[k,o]
// block=(i=blockIdx.x, rg=blockIdx.y), threads o: coalesced bases reads.
__global__ void k_combineT1(const float* __restrict__ bases, const float* __restrict__ comp,
                            const float* __restrict__ root, u16* __restrict__ Bn) {
  int i = blockIdx.x, rg = blockIdx.y, o = threadIdx.x;   // 256 x 9 x 256
  float v; int j;
  if (rg < RR) {
    float acc = 0.f;
    #pragma unroll
    for (int b = 0; b < NBASES; ++b)
      acc += comp[rg * NBASES + b] * bases[(size_t)b * 65536 + i * 256 + o];
    v = acc; j = rg * 256 + o;
  } else {
    v = root[i * 256 + o]; j = 2048 + o;
  }
  Bn[(size_t)j * KD + i] = f2b(v);
}

__global__ void k_combineT2(const float* __restrict__ bases, const float* __restrict__ comp,
                            const float* __restrict__ root, u16* __restrict__ Bn) {
  int i = blockIdx.x, rg = blockIdx.y, o = threadIdx.x;   // 256 x 9 x 128
  float v; int j;
  if (rg < RR) {
    float acc = 0.f;
    #pragma unroll
    for (int b = 0; b < NBASES; ++b)
      acc += comp[rg * NBASES + b] * bases[(size_t)b * 32768 + i * 128 + o];
    v = acc; j = rg * 128 + o;
  } else {
    v = root[i * 128 + o]; j = 1024 + o;
  }
  Bn[(size_t)j * KD + i] = f2b(v);
}

// fixed-stride bucket: cnt doubles as cursor
__global__ void k_bucket_fs(const int* __restrict__ ei, const int* __restrict__ ety,
                            int* __restrict__ cnt, int* __restrict__ esrc) {
  int e = blockIdx.x * 256 + threadIdx.x;
  if (e < EE) {
    int seg = ei[EE + e] * RR + ety[e];
    int pos = atomicAdd(&cnt[seg], 1);
    if (pos < CAP) esrc[seg * CAP + pos] = ei[e];
  }
}

// ------- launch -------------------------------------------------------------
extern "C" void kernel_launch(void* const* d_in, const int* in_sizes, int n_in,
                              void* d_out, int out_size, void* d_ws, size_t ws_size,
                              hipStream_t stream) {
  const float* x      = (const float*)d_in[0];
  const int*   ei     = (const int*)d_in[1];
  const int*   ety    = (const int*)d_in[2];
  const float* bases1 = (const float*)d_in[3];
  const float* comp1  = (const float*)d_in[4];
  const float* root1  = (const float*)d_in[5];
  const float* bias1  = (const float*)d_in[6];
  const float* bases2 = (const float*)d_in[7];
  const float* comp2  = (const float*)d_in[8];
  const float* root2  = (const float*)d_in[9];
  const float* bias2  = (const float*)d_in[10];
  float* out = (float*)d_out;

  char* p = (char*)d_ws;
  auto alloc = [&](size_t bytes) {
    char* q = p; p += (bytes + 255) & ~(size_t)255; return q;
  };
  u16* Y    = (u16*)alloc((size_t)MPAD * NC1 * 2);     // 138.6 MB, reused layer 2
  u16* xb   = (u16*)alloc((size_t)MPAD * KD * 2);
  u16* z1b  = (u16*)alloc((size_t)MPAD * KD * 2);
  u16* Bn1  = (u16*)alloc((size_t)NC1 * KD * 2);
  u16* Bn2  = (u16*)alloc((size_t)NC2 * KD * 2);
  int* cnt  = (int*)alloc((size_t)NSEG * 4);
  int* esrc = (int*)alloc((size_t)NSEG * CAP * 4);     // 30.7 MB fixed-stride

  // fixed-stride CSR (no scans)
  hipMemsetAsync(cnt, 0, (size_t)NSEG * 4, stream);
  k_bucket_fs<<<(EE + 255) / 256, 256, 0, stream>>>(ei, ety, cnt, esrc);

  // weights + input cast
  k_cast_x<<<NN * KD / 4 / 256, 256, 0, stream>>>(x, xb);
  k_combineT1<<<dim3(256, 9), 256, 0, stream>>>(bases1, comp1, root1, Bn1);
  k_combineT2<<<dim3(256, 9), 128, 0, stream>>>(bases2, comp2, root2, Bn2);

  // layer 1: Y = xb @ Bn1^T; z1b = leaky(agg(Y) + bias1)
  k_gemm_y<NC1><<<dim3(NC1 / 128, 470), 512, 0, stream>>>(xb, Bn1, Y);
  k_agg<256, false><<<NN, 256, 0, stream>>>(Y, cnt, esrc, bias1, z1b, nullptr);

  // layer 2: Y = z1b @ Bn2^T; out = agg(Y) + bias2
  k_gemm_y<NC2><<<dim3(NC2 / 128, 470), 512, 0, stream>>>(z1b, Bn2, Y);
  k_agg<128, true><<<NN, 256, 0, stream>>>(Y, cnt, esrc, bias2, nullptr, out);
}

// Round 6
// 347.481 us; speedup vs baseline: 1.3292x; 1.0775x over previous
//
#include <hip/hip_runtime.h>
#include <hip/hip_bf16.h>
#include <stdint.h>

#define NN     30000
#define MPAD   30080          // 470 * 64 = 235 * 128
#define RR     8
#define NBASES 30
#define KD     256            // K of both GEMMs (in-dim of each layer)
#define EE     480000
#define NSEG   (NN * RR)
#define BK     64             // K-step; 8 chunks of 8 bf16 per row
#define CAP    32             // fixed segment capacity (Poisson(2): P(>32)~1e-20)
#define NC1    2304           // Y1 cols: 8*256 rel + 256 self
#define NC2    1152           // Y2 cols: 8*128 rel + 128 self

typedef unsigned short u16;
typedef __attribute__((ext_vector_type(8))) short bf16x8;   // 8 bf16 = 4 VGPRs
typedef __attribute__((ext_vector_type(4))) float f32x4;

__device__ __forceinline__ u16 f2b(float f) {
  union { float f; uint32_t u; } v; v.f = f;
  return (u16)((v.u + 0x7fffu + ((v.u >> 16) & 1u)) >> 16);   // RNE
}
__device__ __forceinline__ float b2f(u16 h) {
  union { uint32_t u; float f; } v; v.u = ((uint32_t)h) << 16;
  return v.f;
}

__device__ __forceinline__ void gl_lds16(const void* g, void* l) {
  __builtin_amdgcn_global_load_lds((__attribute__((address_space(1))) void*)g,
                                   (__attribute__((address_space(3))) void*)l,
                                   16, 0, 0);
}

// ------- dense transform GEMM: Y[M x NCOLS] = A[M x 256] @ Bn^T ------------
// r6: M-tile 64 -> 128 (wave tile 32x64, 4m x 2n waves) for 1.5x FLOPs per
// staged byte; staging/swizzle/compute pattern byte-identical otherwise.
// Epilogue routes acc through LDS (two 64-row passes) so Y is written in
// 256B-contiguous row chunks.
template<int NCOLS>
__global__ __launch_bounds__(512, 2)
void k_gemm_y(const u16* __restrict__ A, const u16* __restrict__ Bn,
              u16* __restrict__ Y) {
  constexpr int NT = 128, MT = 128;
  constexpr int MI = 2, NI = 4;         // wave tile 32 x 64
  constexpr int NKI = KD / BK;          // 4
  __shared__ __align__(16) char smem[65536];
  u16 (*Alds)[MT * BK] = (u16(*)[MT * BK])smem;                    // 2 x 16KB
  u16 (*Blds)[NT * BK] = (u16(*)[NT * BK])(smem + 2 * MT * BK * 2);// 2 x 16KB
  float* eps = (float*)smem;            // epilogue f32 tile [64][132]
  const int tid = threadIdx.x;          // 512 threads = 8 waves
  const int w = tid >> 6, lane = tid & 63;
  const int bn = blockIdx.x * NT, bm = blockIdx.y * MT;
  const int wm = (w >> 1) * 32;         // 4 m-wave-groups x 32 rows
  const int wn = (w & 1) * 64;          // 2 n-waves
  const int l15 = lane & 15, l4 = lane >> 4;

  f32x4 acc[MI][NI];
  #pragma unroll
  for (int mi = 0; mi < MI; ++mi)
    #pragma unroll
    for (int ni = 0; ni < NI; ++ni) acc[mi][ni] = (f32x4){0.f, 0.f, 0.f, 0.f};

  auto stage = [&](int buf, int k0) {
    // A tile: 128 rows x 8 chunks = 1024 chunks of 16B, 2 per thread
    #pragma unroll
    for (int it = 0; it < 2; ++it) {
      int chb = it * 512 + w * 64;       // wave-uniform dest base
      int ch = chb + lane;
      int row = ch >> 3, pc = ch & 7;
      int lc = pc ^ (row & 7);
      gl_lds16(&A[(size_t)(bm + row) * KD + k0 + lc * 8], &Alds[buf][chb * 8]);
    }
    // B tile: 128 rows x 8 chunks = 1024 chunks, 2 per thread
    #pragma unroll
    for (int it = 0; it < 2; ++it) {
      int chb = it * 512 + w * 64;
      int ch = chb + lane;
      int row = ch >> 3, pc = ch & 7;
      int lc = pc ^ (row & 7);
      gl_lds16(&Bn[(size_t)(bn + row) * KD + k0 + lc * 8], &Blds[buf][chb * 8]);
    }
  };

  stage(0, 0);
  __syncthreads();
  int buf = 0;
  for (int t = 0; t < NKI; ++t) {
    if (t + 1 < NKI) stage(buf ^ 1, (t + 1) * BK);
    #pragma unroll
    for (int s = 0; s < 2; ++s) {        // two 32-K steps
      bf16x8 av[MI], bv[NI];
      #pragma unroll
      for (int mi = 0; mi < MI; ++mi) {
        int row = wm + mi * 16 + l15;
        int pc = (4 * s + l4) ^ (row & 7);
        av[mi] = *(const bf16x8*)&Alds[buf][row * BK + pc * 8];
      }
      #pragma unroll
      for (int ni = 0; ni < NI; ++ni) {
        int row = wn + ni * 16 + l15;
        int pc = (4 * s + l4) ^ (row & 7);
        bv[ni] = *(const bf16x8*)&Blds[buf][row * BK + pc * 8];
      }
      #pragma unroll
      for (int mi = 0; mi < MI; ++mi)
        #pragma unroll
        for (int ni = 0; ni < NI; ++ni)
          acc[mi][ni] = __builtin_amdgcn_mfma_f32_16x16x32_bf16(av[mi], bv[ni], acc[mi][ni], 0, 0, 0);
    }
    __syncthreads();
    buf ^= 1;
  }

  // epilogue via LDS, two 64-row passes (eps aliases staging buffers; the
  // loop's final __syncthreads precedes first write).
  #pragma unroll
  for (int p = 0; p < 2; ++p) {
    if ((wm >> 6) == p) {
      #pragma unroll
      for (int mi = 0; mi < MI; ++mi)
        #pragma unroll
        for (int ni = 0; ni < NI; ++ni) {
          int col = wn + ni * 16 + l15;
          #pragma unroll
          for (int v = 0; v < 4; ++v) {
            int row = (wm & 63) + mi * 16 + l4 * 4 + v;
            eps[row * 132 + col] = acc[mi][ni][v];
          }
        }
    }
    __syncthreads();
    {
      int row = tid >> 3, oc = tid & 7;  // 64 rows x 8 col-octets (16 cols each)
      const float* src = &eps[row * 132 + oc * 16];
      uint4 o[2];
      #pragma unroll
      for (int hh = 0; hh < 2; ++hh) {
        float f0 = src[hh*8+0], f1 = src[hh*8+1], f2 = src[hh*8+2], f3 = src[hh*8+3];
        float f4 = src[hh*8+4], f5 = src[hh*8+5], f6 = src[hh*8+6], f7 = src[hh*8+7];
        o[hh].x = ((uint32_t)f2b(f1) << 16) | (uint32_t)f2b(f0);
        o[hh].y = ((uint32_t)f2b(f3) << 16) | (uint32_t)f2b(f2);
        o[hh].z = ((uint32_t)f2b(f5) << 16) | (uint32_t)f2b(f4);
        o[hh].w = ((uint32_t)f2b(f7) << 16) | (uint32_t)f2b(f6);
      }
      u16* dst = &Y[(size_t)(bm + p * 64 + row) * NCOLS + bn + oc * 16];
      *(uint4*)dst = o[0];
      *(uint4*)(dst + 8) = o[1];
    }
    __syncthreads();
  }
}

// ------- aggregate: out[d] = sum_r inv_r * sum_e Y[src_e, r-blk] + self + bias
// r6: one HALFWAVE owns one dst end-to-end (32 lanes x CW cols = full D).
// No LDS, no barriers, no cross-thread reduce.  8 dsts per 256-thr block
// (3750 blocks).  cnt (2 x int4) and first-4 esrc per rel (8 x int4,
// data-independent addresses) prefetched for MLP; n>4 tail serial (5.3%).
// Per-rel sum-then-scale (t, then fma(inv,t,a)) preserves r5 rounding shape.
template<int D, bool LAST>
__global__ __launch_bounds__(256)
void k_agg(const u16* __restrict__ Y, const int* __restrict__ cnt,
           const int* __restrict__ esrc, const float* __restrict__ bias,
           u16* __restrict__ ob, float* __restrict__ of) {
  constexpr int YW = 9 * D;             // Y row width
  constexpr int CW = D / 32;            // cols per lane (8 or 4)
  const int tid = threadIdx.x;
  const int h = tid >> 5, ln = tid & 31;
  const int d = blockIdx.x * 8 + h;     // grid 3750 x 8 = 30000 exact

  int cn[8];
  {
    int4 c0 = *(const int4*)&cnt[d << 3];
    int4 c1 = *(const int4*)&cnt[(d << 3) + 4];
    cn[0]=c0.x; cn[1]=c0.y; cn[2]=c0.z; cn[3]=c0.w;
    cn[4]=c1.x; cn[5]=c1.y; cn[6]=c1.z; cn[7]=c1.w;
  }
  int4 q[8];
  #pragma unroll
  for (int r = 0; r < 8; ++r)
    q[r] = *(const int4*)&esrc[((d << 3) + r) * CAP];

  float a[CW];
  #pragma unroll
  for (int j = 0; j < CW; ++j) a[j] = 0.f;

  #pragma unroll
  for (int r = 0; r < 8; ++r) {
    int n = cn[r] < CAP ? cn[r] : CAP;
    if (n == 0) continue;
    float t[CW];
    #pragma unroll
    for (int j = 0; j < CW; ++j) t[j] = 0.f;
    const int qsrc[4] = {q[r].x, q[r].y, q[r].z, q[r].w};
    #pragma unroll
    for (int e = 0; e < 4; ++e) {
      if (e < n) {
        int sr = qsrc[e];
        if constexpr (CW == 8) {
          uint4 v = *(const uint4*)&Y[(size_t)sr * YW + r * D + ln * 8];
          t[0]+=b2f((u16)v.x); t[1]+=b2f((u16)(v.x>>16));
          t[2]+=b2f((u16)v.y); t[3]+=b2f((u16)(v.y>>16));
          t[4]+=b2f((u16)v.z); t[5]+=b2f((u16)(v.z>>16));
          t[6]+=b2f((u16)v.w); t[7]+=b2f((u16)(v.w>>16));
        } else {
          uint2 v = *(const uint2*)&Y[(size_t)sr * YW + r * D + ln * 4];
          t[0]+=b2f((u16)v.x); t[1]+=b2f((u16)(v.x>>16));
          t[2]+=b2f((u16)v.y); t[3]+=b2f((u16)(v.y>>16));
        }
      }
    }
    #pragma unroll 1
    for (int e = 4; e < n; ++e) {
      int sr = esrc[((d << 3) + r) * CAP + e];
      if constexpr (CW == 8) {
        uint4 v = *(const uint4*)&Y[(size_t)sr * YW + r * D + ln * 8];
        t[0]+=b2f((u16)v.x); t[1]+=b2f((u16)(v.x>>16));
        t[2]+=b2f((u16)v.y); t[3]+=b2f((u16)(v.y>>16));
        t[4]+=b2f((u16)v.z); t[5]+=b2f((u16)(v.z>>16));
        t[6]+=b2f((u16)v.w); t[7]+=b2f((u16)(v.w>>16));
      } else {
        uint2 v = *(const uint2*)&Y[(size_t)sr * YW + r * D + ln * 4];
        t[0]+=b2f((u16)v.x); t[1]+=b2f((u16)(v.x>>16));
        t[2]+=b2f((u16)v.y); t[3]+=b2f((u16)(v.y>>16));
      }
    }
    float inv = 1.f / (float)n;
    #pragma unroll
    for (int j = 0; j < CW; ++j) a[j] = fmaf(inv, t[j], a[j]);
  }

  // self term + bias + activation + store (halfwave-local, no reduce)
  if constexpr (CW == 8) {
    uint4 sv = *(const uint4*)&Y[(size_t)d * YW + 8 * D + ln * 8];
    float s[8] = { b2f((u16)sv.x), b2f((u16)(sv.x>>16)),
                   b2f((u16)sv.y), b2f((u16)(sv.y>>16)),
                   b2f((u16)sv.z), b2f((u16)(sv.z>>16)),
                   b2f((u16)sv.w), b2f((u16)(sv.w>>16)) };
    float4 b0 = *(const float4*)&bias[ln * 8];
    float4 b1 = *(const float4*)&bias[ln * 8 + 4];
    float vv[8];
    vv[0]=a[0]+s[0]+b0.x; vv[1]=a[1]+s[1]+b0.y;
    vv[2]=a[2]+s[2]+b0.z; vv[3]=a[3]+s[3]+b0.w;
    vv[4]=a[4]+s[4]+b1.x; vv[5]=a[5]+s[5]+b1.y;
    vv[6]=a[6]+s[6]+b1.z; vv[7]=a[7]+s[7]+b1.w;
    if (!LAST) {
      #pragma unroll
      for (int j = 0; j < 8; ++j) vv[j] = vv[j] > 0.f ? vv[j] : 0.01f * vv[j];
      uint4 o;
      o.x = ((uint32_t)f2b(vv[1]) << 16) | (uint32_t)f2b(vv[0]);
      o.y = ((uint32_t)f2b(vv[3]) << 16) | (uint32_t)f2b(vv[2]);
      o.z = ((uint32_t)f2b(vv[5]) << 16) | (uint32_t)f2b(vv[4]);
      o.w = ((uint32_t)f2b(vv[7]) << 16) | (uint32_t)f2b(vv[6]);
      *(uint4*)&ob[(size_t)d * KD + ln * 8] = o;
    } else {
      float4 o0 = {vv[0], vv[1], vv[2], vv[3]};
      float4 o1 = {vv[4], vv[5], vv[6], vv[7]};
      *(float4*)&of[(size_t)d * 256 + ln * 8] = o0;       // unused path (D=256 is layer1)
      *(float4*)&of[(size_t)d * 256 + ln * 8 + 4] = o1;
    }
  } else {
    uint2 sv = *(const uint2*)&Y[(size_t)d * YW + 8 * D + ln * 4];
    float s[4] = { b2f((u16)sv.x), b2f((u16)(sv.x>>16)),
                   b2f((u16)sv.y), b2f((u16)(sv.y>>16)) };
    float4 b0 = *(const float4*)&bias[ln * 4];
    float vv[4];
    vv[0]=a[0]+s[0]+b0.x; vv[1]=a[1]+s[1]+b0.y;
    vv[2]=a[2]+s[2]+b0.z; vv[3]=a[3]+s[3]+b0.w;
    if (!LAST) {
      #pragma unroll
      for (int j = 0; j < 4; ++j) vv[j] = vv[j] > 0.f ? vv[j] : 0.01f * vv[j];
      uint2 o;
      o.x = ((uint32_t)f2b(vv[1]) << 16) | (uint32_t)f2b(vv[0]);
      o.y = ((uint32_t)f2b(vv[3]) << 16) | (uint32_t)f2b(vv[2]);
      *(uint2*)&ob[(size_t)d * KD + ln * 4] = o;
    } else {
      float4 o = {vv[0], vv[1], vv[2], vv[3]};
      *(float4*)&of[(size_t)d * 128 + ln * 4] = o;
    }
  }
}

// ------- small kernels ------------------------------------------------------
__global__ void k_cast_x(const float* __restrict__ x, u16* __restrict__ xb) {
  int t = blockIdx.x * 256 + threadIdx.x;
  if (t < NN * KD / 4) {
    float4 v = ((const float4*)x)[t];
    union { u16 h[4]; uint2 u; } p;
    p.h[0] = f2b(v.x); p.h[1] = f2b(v.y); p.h[2] = f2b(v.z); p.h[3] = f2b(v.w);
    ((uint2*)xb)[t] = p.u;
  }
}

// Bn1[j*256 + k]: j=r*256+o -> sum_b comp1[r,b]*bases1[b,k,o]; j=2048+o -> root1[k,o]
__global__ void k_combineT1(const float* __restrict__ bases, const float* __restrict__ comp,
                            const float* __restrict__ root, u16* __restrict__ Bn) {
  int i = blockIdx.x, rg = blockIdx.y, o = threadIdx.x;   // 256 x 9 x 256
  float v; int j;
  if (rg < RR) {
    float acc = 0.f;
    #pragma unroll
    for (int b = 0; b < NBASES; ++b)
      acc += comp[rg * NBASES + b] * bases[(size_t)b * 65536 + i * 256 + o];
    v = acc; j = rg * 256 + o;
  } else {
    v = root[i * 256 + o]; j = 2048 + o;
  }
  Bn[(size_t)j * KD + i] = f2b(v);
}

__global__ void k_combineT2(const float* __restrict__ bases, const float* __restrict__ comp,
                            const float* __restrict__ root, u16* __restrict__ Bn) {
  int i = blockIdx.x, rg = blockIdx.y, o = threadIdx.x;   // 256 x 9 x 128
  float v; int j;
  if (rg < RR) {
    float acc = 0.f;
    #pragma unroll
    for (int b = 0; b < NBASES; ++b)
      acc += comp[rg * NBASES + b] * bases[(size_t)b * 32768 + i * 128 + o];
    v = acc; j = rg * 128 + o;
  } else {
    v = root[i * 128 + o]; j = 1024 + o;
  }
  Bn[(size_t)j * KD + i] = f2b(v);
}

// fixed-stride bucket: cnt doubles as cursor
__global__ void k_bucket_fs(const int* __restrict__ ei, const int* __restrict__ ety,
                            int* __restrict__ cnt, int* __restrict__ esrc) {
  int e = blockIdx.x * 256 + threadIdx.x;
  if (e < EE) {
    int seg = ei[EE + e] * RR + ety[e];
    int pos = atomicAdd(&cnt[seg], 1);
    if (pos < CAP) esrc[seg * CAP + pos] = ei[e];
  }
}

// ------- launch -------------------------------------------------------------
extern "C" void kernel_launch(void* const* d_in, const int* in_sizes, int n_in,
                              void* d_out, int out_size, void* d_ws, size_t ws_size,
                              hipStream_t stream) {
  const float* x      = (const float*)d_in[0];
  const int*   ei     = (const int*)d_in[1];
  const int*   ety    = (const int*)d_in[2];
  const float* bases1 = (const float*)d_in[3];
  const float* comp1  = (const float*)d_in[4];
  const float* root1  = (const float*)d_in[5];
  const float* bias1  = (const float*)d_in[6];
  const float* bases2 = (const float*)d_in[7];
  const float* comp2  = (const float*)d_in[8];
  const float* root2  = (const float*)d_in[9];
  const float* bias2  = (const float*)d_in[10];
  float* out = (float*)d_out;

  char* p = (char*)d_ws;
  auto alloc = [&](size_t bytes) {
    char* q = p; p += (bytes + 255) & ~(size_t)255; return q;
  };
  u16* Y    = (u16*)alloc((size_t)MPAD * NC1 * 2);     // 138.6 MB, reused layer 2
  u16* xb   = (u16*)alloc((size_t)MPAD * KD * 2);
  u16* z1b  = (u16*)alloc((size_t)MPAD * KD * 2);
  u16* Bn1  = (u16*)alloc((size_t)NC1 * KD * 2);
  u16* Bn2  = (u16*)alloc((size_t)NC2 * KD * 2);
  int* cnt  = (int*)alloc((size_t)NSEG * 4);
  int* esrc = (int*)alloc((size_t)NSEG * CAP * 4);     // 30.7 MB fixed-stride

  // fixed-stride CSR (no scans)
  hipMemsetAsync(cnt, 0, (size_t)NSEG * 4, stream);
  k_bucket_fs<<<(EE + 255) / 256, 256, 0, stream>>>(ei, ety, cnt, esrc);

  // weights + input cast
  k_cast_x<<<NN * KD / 4 / 256, 256, 0, stream>>>(x, xb);
  k_combineT1<<<dim3(256, 9), 256, 0, stream>>>(bases1, comp1, root1, Bn1);
  k_combineT2<<<dim3(256, 9), 128, 0, stream>>>(bases2, comp2, root2, Bn2);

  // layer 1: Y = xb @ Bn1^T; z1b = leaky(agg(Y) + bias1)
  k_gemm_y<NC1><<<dim3(NC1 / 128, MPAD / 128), 512, 0, stream>>>(xb, Bn1, Y);
  k_agg<256, false><<<NN / 8, 256, 0, stream>>>(Y, cnt, esrc, bias1, z1b, nullptr);

  // layer 2: Y = z1b @ Bn2^T; out = agg(Y) + bias2
  k_gemm_y<NC2><<<dim3(NC2 / 128, MPAD / 128), 512, 0, stream>>>(z1b, Bn2, Y);
  k_agg<128, true><<<NN / 8, 256, 0, stream>>>(Y, cnt, esrc, bias2, nullptr, out);
}